// Round 6
// baseline (5414.402 us; speedup 1.0000x reference)
//
#include <hip/hip_runtime.h>
#include <cstdint>
#include <cstddef>

// CCDecoder: 16-step input-feeding LSTM + Luong attention decoder.
// B=256, S=512, T=16, H=1024, E=512.
// R6 = R5 + race fix: trailing s_barrier after the GEMM k-loop. R5's removal
//     of the per-iter trailing barrier let a fast wave's NEXT-call prologue
//     stages (buf 0,1,2,3 pre-barrier) overwrite buf 2 while a laggard wave
//     of the previous call still read buf (nt-1)%5==2 (phase 0b's 16
//     back-to-back gemm_tile calls). Within-call pipeline proven safe.
//     Persistent kernel + lean sense-reversing grid barrier (agent scope).

#define B_ 256
#define S_ 512
#define T_ 16
#define H_ 1024
#define E_ 512
#define NBUF 5

typedef unsigned short u16;
using short8 = __attribute__((ext_vector_type(8))) short;
using f32x4  = __attribute__((ext_vector_type(4))) float;

__device__ __forceinline__ float bf2f(u16 u) {
  union { uint32_t i; float f; } v; v.i = ((uint32_t)u) << 16; return v.f;
}
__device__ __forceinline__ u16 f2bf(float f) {
  union { uint32_t i; float f; } v; v.f = f;
  uint32_t r = v.i + 0x7fffu + ((v.i >> 16) & 1u);
  return (u16)(r >> 16);
}
__device__ __forceinline__ float sigmoidf_(float x) { return 1.f / (1.f + __expf(-x)); }

__device__ __forceinline__ void gload_lds16(const void* g, void* l) {
  __builtin_amdgcn_global_load_lds(
      (const __attribute__((address_space(1))) void*)g,
      (__attribute__((address_space(3))) void*)l, 16, 0, 0);
}

// Lean sense-reversing grid barrier. bar[0]=count, bar[1]=generation.
// Zeroed via hipMemsetAsync before each kernel launch.
__device__ __forceinline__ void gbar(int* bar, int nblk) {
  __syncthreads();   // drains vmcnt/lgkm for all waves (HIP barrier semantics)
  if (threadIdx.x == 0) {
    int g = __hip_atomic_load(bar + 1, __ATOMIC_RELAXED, __HIP_MEMORY_SCOPE_AGENT);
    int a = __hip_atomic_fetch_add(bar, 1, __ATOMIC_ACQ_REL, __HIP_MEMORY_SCOPE_AGENT);
    if (a == nblk - 1) {
      __hip_atomic_store(bar, 0, __ATOMIC_RELAXED, __HIP_MEMORY_SCOPE_AGENT);
      __hip_atomic_store(bar + 1, g + 1, __ATOMIC_RELEASE, __HIP_MEMORY_SCOPE_AGENT);
    } else {
      while (__hip_atomic_load(bar + 1, __ATOMIC_ACQUIRE, __HIP_MEMORY_SCOPE_AGENT) == g)
        __builtin_amdgcn_s_sleep(8);
    }
  }
  __syncthreads();
}

struct Reg2 { const u16* A; int lda; const u16* B; int ldb; int kt; };

struct MegaP {
  const float* trg_emb; const float* h0; const float* c0; const float* ctx;
  const int* src_len;
  const float* W_ih; const float* W_hh; const float* b_ih; const float* b_hh;
  const float* W_in; const float* W_out;
  float* out;
  int* bar;
  u16* wWih; u16* wWhh; u16* wWin; u16* wWout; u16* wemb;
  float* wbsum; float* wh32; float* wc; float* wGemb;
  u16* whbf0; u16* whbf1; u16* whtbf; u16* wtgt; u16* wwbf; u16* wctx;
  int ctx_bf;
};

union SMem {
  struct { u16 A[NBUF][4096]; u16 B[NBUF][4096]; } g;              // 80 KB
  struct { float facc[8][1024]; float fm[16]; float fl[16]; } a;   // 32.1 KB
};

// One 64x64 output tile, 16 waves (4x4 wave grid, one 16x16 frag each).
// 5-buffer LDS, 3-deep prefetch, counted vmcnt, ONE s_barrier per k-iter,
// plus ONE trailing s_barrier after the loop (call-boundary safety).
// Exactly 1 load/thread/stage (wave-uniform -> vmcnt count valid).
template <int EPI>  // 0: fp32->Cf(ldc 4096)  1: bf16->Cb  2: tanh->out+Cb  3: fused LSTM
__device__ void gemm_tile(SMem* sm, const int tid, const int m0, const int n0,
                          const Reg2 r0, const Reg2 r1,
                          float* __restrict__ Cf, u16* __restrict__ Cb,
                          const float* __restrict__ Ci,
                          const float* __restrict__ bsum,
                          float* __restrict__ cst, float* __restrict__ h32o,
                          u16* __restrict__ hbfo, const int tstep) {
  const int lane = tid & 63;
  const int wave = tid >> 6;
  const int nt = r0.kt + r1.kt;
  const int wm = ((wave >> 2) << 4);
  const int wn = ((wave & 3) << 4);
  const int row16 = lane & 15;
  const int kg = lane >> 4;

  auto stage = [&](int ti, int buf) {
    const bool fst = ti < r0.kt;
    const u16* Ap = fst ? r0.A : r1.A;
    const u16* Bp = fst ? r0.B : r1.B;
    const int lda = fst ? r0.lda : r1.lda;
    const int ldb = fst ? r0.ldb : r1.ldb;
    const int kr = (fst ? ti : ti - r0.kt) << 6;
    if (tid < 512) {
      const int row = tid >> 3, qs = tid & 7;
      gload_lds16(Ap + (size_t)(m0 + row) * lda + kr + ((qs ^ (row & 7)) << 3),
                  (char*)&sm->g.A[buf][0] + (wave << 10));
    } else {
      const int c = tid - 512;
      const int row = c >> 3, qs = c & 7;
      gload_lds16(Bp + (size_t)(n0 + row) * ldb + kr + ((qs ^ (row & 7)) << 3),
                  (char*)&sm->g.B[buf][0] + ((wave - 8) << 10));
    }
  };

  f32x4 acc = {0.f, 0.f, 0.f, 0.f};
  stage(0, 0);
  if (nt > 1) stage(1, 1);
  if (nt > 2) stage(2, 2);
  for (int ti = 0; ti < nt; ++ti) {
    const int buf = ti % NBUF;
    if (ti + 3 < nt) {
      stage(ti + 3, (ti + 3) % NBUF);
      asm volatile("s_waitcnt vmcnt(3)" ::: "memory");
    } else if (ti + 2 < nt) {
      asm volatile("s_waitcnt vmcnt(2)" ::: "memory");
    } else if (ti + 1 < nt) {
      asm volatile("s_waitcnt vmcnt(1)" ::: "memory");
    } else {
      asm volatile("s_waitcnt vmcnt(0)" ::: "memory");
    }
    __builtin_amdgcn_s_barrier();
    __builtin_amdgcn_sched_barrier(0);
    const int Ra = wm + row16;
    const int Rb = wn + row16;
    short8 a0 = *(const short8*)((const char*)&sm->g.A[buf][0] + (size_t)((Ra << 3) + (kg ^ (Ra & 7))) * 16);
    short8 b0 = *(const short8*)((const char*)&sm->g.B[buf][0] + (size_t)((Rb << 3) + (kg ^ (Rb & 7))) * 16);
    short8 a1 = *(const short8*)((const char*)&sm->g.A[buf][0] + (size_t)((Ra << 3) + ((4 + kg) ^ (Ra & 7))) * 16);
    short8 b1 = *(const short8*)((const char*)&sm->g.B[buf][0] + (size_t)((Rb << 3) + ((4 + kg) ^ (Rb & 7))) * 16);
    asm volatile("s_waitcnt lgkmcnt(0)" ::: "memory");
    __builtin_amdgcn_sched_barrier(0);
    acc = __builtin_amdgcn_mfma_f32_16x16x32_bf16(a0, b0, acc, 0, 0, 0);
    acc = __builtin_amdgcn_mfma_f32_16x16x32_bf16(a1, b1, acc, 0, 0, 0);
    __builtin_amdgcn_sched_barrier(0);
  }
  // Trailing barrier: all waves past their final lgkmcnt(0) -> all LDS reads
  // done before any wave can reach a subsequent call's prologue stages.
  __builtin_amdgcn_s_barrier();
  __builtin_amdgcn_sched_barrier(0);
  // C/D layout: col = lane&15, row = (lane>>4)*4 + r  [m89-verified]
#pragma unroll
  for (int r = 0; r < 4; ++r) {
    const int row = m0 + wm + (kg << 2) + r;
    const int col = n0 + wn + row16;
    float v = acc[r];
    if (EPI == 0) {
      Cf[(size_t)row * 4096 + col] = v;
    } else if (EPI == 1) {
      Cb[row * H_ + col] = f2bf(v);
    } else if (EPI == 2) {
      float tv = tanhf(v);
      Cf[(size_t)row * (T_ * H_) + tstep * H_ + col] = tv;
      Cb[row * H_ + col] = f2bf(tv);
    } else {
      // gate-interleaved: col&3 = gate(i,f,g,o), col>>2 = unit
      v += Ci[(size_t)row * (T_ * 4096) + col] + bsum[col];
      float v1 = __shfl_xor(v, 1);
      float v2 = __shfl_xor(v, 2);
      float v3 = __shfl_xor(v, 3);
      if ((lane & 3) == 0) {
        const int u = col >> 2;
        float iv = sigmoidf_(v);
        float fv = sigmoidf_(v1);
        float gv = tanhf(v2);
        float ov = sigmoidf_(v3);
        float cn = fv * cst[row * H_ + u] + iv * gv;
        float hn = ov * tanhf(cn);
        cst[row * H_ + u] = cn;
        h32o[row * H_ + u] = hn;
        hbfo[row * H_ + u] = f2bf(hn);
      }
    }
  }
}

// facc conflict-free index: element held by (lane, j) stored at j*64+((lane+4j)&63)
__device__ __forceinline__ int fidx(int lane, int j) {
  return (j << 6) + ((lane + (j << 2)) & 63);
}

// Online-softmax attention for batch row `bid`. 16 waves stride s; per wave
// running (m,l,acc[16]); merge 16->8 in LDS -> final normalize.
__device__ void attn_phase(SMem* sm, const MegaP& P, const int bid, const int tid) {
  const int lane = tid & 63;
  const int wave = tid >> 6;
  const int len = P.src_len[bid];
  float tg[16];
  {
    const u16* tp = P.wtgt + bid * H_ + lane * 16;
    short8 v1 = *(const short8*)tp;
    short8 v2 = *(const short8*)(tp + 8);
#pragma unroll
    for (int j = 0; j < 8; ++j) { tg[j] = bf2f((u16)v1[j]); tg[8 + j] = bf2f((u16)v2[j]); }
  }
  float m = -1e30f, l = 0.f;
  float acc[16];
#pragma unroll
  for (int j = 0; j < 16; ++j) acc[j] = 0.f;

  if (P.ctx_bf) {
    const u16* cb = P.wctx + (size_t)bid * (S_ * H_);
    for (int s = wave; s < len; s += 16) {
      const u16* cr = cb + (size_t)s * H_ + lane * 16;
      short8 v1 = *(const short8*)cr;
      short8 v2 = *(const short8*)(cr + 8);
      float cf[16];
#pragma unroll
      for (int j = 0; j < 8; ++j) { cf[j] = bf2f((u16)v1[j]); cf[8 + j] = bf2f((u16)v2[j]); }
      float x = 0.f;
#pragma unroll
      for (int j = 0; j < 16; ++j) x += cf[j] * tg[j];
#pragma unroll
      for (int off = 1; off < 64; off <<= 1) x += __shfl_xor(x, off);
      if (x > m) {                      // wave-uniform after reduce
        float sc_ = __expf(m - x);
        l *= sc_;
#pragma unroll
        for (int j = 0; j < 16; ++j) acc[j] *= sc_;
        m = x;
      }
      float p = __expf(x - m);
      l += p;
#pragma unroll
      for (int j = 0; j < 16; ++j) acc[j] += p * cf[j];
    }
  } else {
    const float* cb = P.ctx + (size_t)bid * (S_ * H_);
    for (int s = wave; s < len; s += 16) {
      const float* cr = cb + (size_t)s * H_ + lane * 16;
      float cf[16];
#pragma unroll
      for (int j4 = 0; j4 < 4; ++j4) {
        float4 v = *(const float4*)(cr + j4 * 4);
        cf[j4 * 4] = v.x; cf[j4 * 4 + 1] = v.y; cf[j4 * 4 + 2] = v.z; cf[j4 * 4 + 3] = v.w;
      }
      float x = 0.f;
#pragma unroll
      for (int j = 0; j < 16; ++j) x += cf[j] * tg[j];
#pragma unroll
      for (int off = 1; off < 64; off <<= 1) x += __shfl_xor(x, off);
      if (x > m) {
        float sc_ = __expf(m - x);
        l *= sc_;
#pragma unroll
        for (int j = 0; j < 16; ++j) acc[j] *= sc_;
        m = x;
      }
      float p = __expf(x - m);
      l += p;
#pragma unroll
      for (int j = 0; j < 16; ++j) acc[j] += p * cf[j];
    }
  }

  if (wave >= 8) {
#pragma unroll
    for (int j = 0; j < 16; ++j) sm->a.facc[wave - 8][fidx(lane, j)] = acc[j];
    if (lane == 0) { sm->a.fm[wave] = m; sm->a.fl[wave] = l; }
  }
  __syncthreads();
  if (wave < 8) {
    float pm = sm->a.fm[8 + wave];
    float pl = sm->a.fl[8 + wave];
    float M = fmaxf(m, pm);
    float e1 = __expf(m - M);
    float e2 = __expf(pm - M);
#pragma unroll
    for (int j = 0; j < 16; ++j) {
      float pv = sm->a.facc[wave][fidx(lane, j)];
      sm->a.facc[wave][fidx(lane, j)] = acc[j] * e1 + pv * e2;
    }
    if (lane == 0) { sm->a.fm[wave] = M; sm->a.fl[wave] = l * e1 + pl * e2; }
  }
  __syncthreads();
  float mstar = -1e30f;
#pragma unroll
  for (int w = 0; w < 8; ++w) mstar = fmaxf(mstar, sm->a.fm[w]);
  float lsum = 0.f, asum = 0.f;
  const int rl = tid >> 4;          // original holder lane
  const int rj = tid & 15;          // original element j
  const int ri = fidx(rl, rj);
#pragma unroll
  for (int w = 0; w < 8; ++w) {
    float e = __expf(sm->a.fm[w] - mstar);
    lsum += sm->a.fl[w] * e;
    asum += sm->a.facc[w][ri] * e;
  }
  P.wwbf[bid * H_ + tid] = f2bf(asum / lsum);
}

__global__ __launch_bounds__(1024, 4) void mega(MegaP P) {
  __shared__ SMem sm;
  const int tid = threadIdx.x;
  const int bid = blockIdx.x;
  const int gtid = bid * 1024 + tid;      // 262144 threads = B_*H_
  const int GSZ = 256 * 1024;

  // ---------------- phase 0a: converts / bias / init ----------------
  for (int i = gtid; i < 4096 * 384; i += GSZ) {        // W_ih 4096x1536 gi
    const int r = i / 384, c4 = i - r * 384;
    const int rp = ((r & 1023) << 2) + (r >> 10);
    float4 v = ((const float4*)P.W_ih)[i];
    ushort4 o; o.x = f2bf(v.x); o.y = f2bf(v.y); o.z = f2bf(v.z); o.w = f2bf(v.w);
    ((ushort4*)P.wWih)[(size_t)rp * 384 + c4] = o;
  }
  for (int i = gtid; i < 4096 * 256; i += GSZ) {        // W_hh 4096x1024 gi
    const int r = i >> 8, c4 = i & 255;
    const int rp = ((r & 1023) << 2) + (r >> 10);
    float4 v = ((const float4*)P.W_hh)[i];
    ushort4 o; o.x = f2bf(v.x); o.y = f2bf(v.y); o.z = f2bf(v.z); o.w = f2bf(v.w);
    ((ushort4*)P.wWhh)[(size_t)rp * 256 + c4] = o;
  }
  {                                                     // W_in 1024x1024
    float4 v = ((const float4*)P.W_in)[gtid];
    ushort4 o; o.x = f2bf(v.x); o.y = f2bf(v.y); o.z = f2bf(v.z); o.w = f2bf(v.w);
    ((ushort4*)P.wWin)[gtid] = o;
  }
  for (int i = gtid; i < 524288; i += GSZ) {            // W_out 1024x2048
    float4 v = ((const float4*)P.W_out)[i];
    ushort4 o; o.x = f2bf(v.x); o.y = f2bf(v.y); o.z = f2bf(v.z); o.w = f2bf(v.w);
    ((ushort4*)P.wWout)[i] = o;
  }
  for (int i = gtid; i < 524288; i += GSZ) {            // emb (B,T,E)
    float4 v = ((const float4*)P.trg_emb)[i];
    ushort4 o; o.x = f2bf(v.x); o.y = f2bf(v.y); o.z = f2bf(v.z); o.w = f2bf(v.w);
    ((ushort4*)P.wemb)[i] = o;
  }
  if (gtid < 4096) {                                    // bias (gi)
    const int cp = ((gtid & 1023) << 2) + (gtid >> 10);
    P.wbsum[cp] = P.b_ih[gtid] + P.b_hh[gtid];
  }
  {                                                     // init state
    float hv = P.h0[gtid];
    P.wh32[gtid] = hv;
    P.wc[gtid] = P.c0[gtid];
    u16 hb = f2bf(hv);
    P.whbf0[gtid] = hb;
    P.whtbf[gtid] = hb;
  }
  if (P.ctx_bf) {
    for (int i = gtid; i < 33554432; i += GSZ) {        // ctx (B,S,H)
      float4 v = ((const float4*)P.ctx)[i];
      ushort4 o; o.x = f2bf(v.x); o.y = f2bf(v.y); o.z = f2bf(v.z); o.w = f2bf(v.w);
      ((ushort4*)P.wctx)[i] = o;
    }
  }
  gbar(P.bar, 256);

  // ---------------- phase 0b: G_emb = emb @ W_ihE^T (4096x4096, K=512) ----
  {
    Reg2 ra = { P.wemb, E_, P.wWih, E_ + H_, 8 };
    Reg2 rb = { nullptr, 0, nullptr, 0, 0 };
    for (int tile = bid; tile < 4096; tile += 256) {
      const int m0 = (tile & 63) << 6;
      const int n0 = (tile >> 6) << 6;
      gemm_tile<0>(&sm, tid, m0, n0, ra, rb, P.wGemb, nullptr,
                   nullptr, nullptr, nullptr, nullptr, nullptr, 0);
    }
  }
  gbar(P.bar, 256);

  // ---------------- 16 decoder steps ----------------
  for (int t = 0; t < T_; ++t) {
    const u16* hcur = (t & 1) ? P.whbf1 : P.whbf0;
    u16* hnxt = (t & 1) ? P.whbf0 : P.whbf1;
    {  // A: gates + fused LSTM  (M=256, N=4096 gi, K=2048) -- 256 tiles
      const int m0 = (bid & 3) << 6;
      const int n0 = (bid >> 2) << 6;
      Reg2 ra = { P.whtbf, H_, P.wWih + E_, E_ + H_, 16 };
      Reg2 rb = { hcur,    H_, P.wWhh,      H_,      16 };
      gemm_tile<3>(&sm, tid, m0, n0, ra, rb, nullptr, nullptr,
                   P.wGemb + t * 4096, P.wbsum, P.wc, P.wh32, hnxt, 0);
    }
    gbar(P.bar, 256);
    if (bid < 64) {  // B: target = h @ W_in^T  (M=256, N=1024, K=1024)
      const int m0 = (bid & 3) << 6;
      const int n0 = (bid >> 2) << 6;
      Reg2 ra = { hnxt, H_, P.wWin, H_, 16 };
      Reg2 rb = { nullptr, 0, nullptr, 0, 0 };
      gemm_tile<1>(&sm, tid, m0, n0, ra, rb, nullptr, P.wtgt,
                   nullptr, nullptr, nullptr, nullptr, nullptr, 0);
    }
    gbar(P.bar, 256);
    attn_phase(&sm, P, bid, tid);   // C: attention (256 blocks = batch rows)
    gbar(P.bar, 256);
    if (bid < 64) {  // D: htilde = tanh([weighted,h] @ W_out^T) (K=2048)
      const int m0 = (bid & 3) << 6;
      const int n0 = (bid >> 2) << 6;
      Reg2 ra = { P.wwbf, H_, P.wWout,      2 * H_, 16 };
      Reg2 rb = { hnxt,   H_, P.wWout + H_, 2 * H_, 16 };
      gemm_tile<2>(&sm, tid, m0, n0, ra, rb, P.out, P.whtbf,
                   nullptr, nullptr, nullptr, nullptr, nullptr, t);
    }
    gbar(P.bar, 256);
  }

  // ---------------- final h, c -> out tail ----------------
  P.out[(size_t)B_ * T_ * H_ + gtid] = P.wh32[gtid];
  P.out[(size_t)B_ * T_ * H_ + B_ * H_ + gtid] = P.wc[gtid];
}

// ---------------------------------------------------------------- host
extern "C" void kernel_launch(void* const* d_in, const int* in_sizes, int n_in,
                              void* d_out, int out_size, void* d_ws, size_t ws_size,
                              hipStream_t stream) {
  char* w = (char*)d_ws;
  MegaP P;
  P.trg_emb = (const float*)d_in[0];
  P.h0      = (const float*)d_in[1];
  P.c0      = (const float*)d_in[2];
  P.ctx     = (const float*)d_in[3];
  P.src_len = (const int*)d_in[4];
  P.W_ih    = (const float*)d_in[5];
  P.W_hh    = (const float*)d_in[6];
  P.b_ih    = (const float*)d_in[7];
  P.b_hh    = (const float*)d_in[8];
  P.W_in    = (const float*)d_in[9];
  P.W_out   = (const float*)d_in[10];
  P.out     = (float*)d_out;

  size_t off = 0;
  auto alloc = [&](size_t bytes) { char* p = w + off; off += bytes; return p; };
  P.bar   = (int*)  alloc(256);        // barrier state (zeroed below)
  P.wWih  = (u16*)  alloc(12582912);   // 4096x1536 bf16 (gi rows)
  P.wWhh  = (u16*)  alloc(8388608);    // 4096x1024 bf16 (gi rows)
  P.wWin  = (u16*)  alloc(2097152);    // 1024x1024
  P.wWout = (u16*)  alloc(4194304);    // 1024x2048
  P.wemb  = (u16*)  alloc(4194304);    // 4096x512
  P.wbsum = (float*)alloc(16384);      // 4096 (gi)
  P.wh32  = (float*)alloc(1048576);    // 256x1024
  P.wc    = (float*)alloc(1048576);
  P.whbf0 = (u16*)  alloc(524288);
  P.whbf1 = (u16*)  alloc(524288);
  P.whtbf = (u16*)  alloc(524288);
  P.wtgt  = (u16*)  alloc(524288);
  P.wwbf  = (u16*)  alloc(524288);
  P.wGemb = (float*)alloc(67108864);   // 4096x4096 fp32
  size_t need_ctx = off + (size_t)268435456;
  P.wctx  = (u16*)  alloc(268435456);  // 256x512x1024 bf16
  P.ctx_bf = (ws_size >= need_ctx) ? 1 : 0;

  hipMemsetAsync(P.bar, 0, 256, stream);
  mega<<<dim3(256), dim3(1024), 0, stream>>>(P);
}

// Round 9
// 2236.651 us; speedup vs baseline: 2.4208x; 2.4208x over previous
//
#include <hip/hip_runtime.h>
#include <cstdint>
#include <cstddef>

// CCDecoder: 16-step input-feeding LSTM + Luong attention decoder.
// B=256, S=512, T=16, H=1024, E=512.
// R9 = R8 with ctx reverted to bf16 (fp8 e4m3 ctx was the sole remaining
//   error source: R8 failed ONLY on c_f at 0.0544 vs 0.0469; R3 with bf16
//   ctx passed at 0.031). fp8 also has no BW win for a single-pass online
//   softmax (score+accumulate read the row once either way).
//   Structure (R8-proven): 64x32 acc/wave GEMM (BM/BN/BK=64, NBUF=4,
//   2-deep prefetch, counted vmcnt 16/8/0), fused LSTM epilogue,
//   attn = W_in GEMV + online softmax + weighted, 3 launches/step,
//   h ping-pong.

#define B_ 256
#define S_ 512
#define T_ 16
#define H_ 1024
#define E_ 512
#define NBUF 4

typedef unsigned short u16;
using short8 = __attribute__((ext_vector_type(8))) short;
using f32x4  = __attribute__((ext_vector_type(4))) float;

__device__ __forceinline__ float bf2f(u16 u) {
  union { uint32_t i; float f; } v; v.i = ((uint32_t)u) << 16; return v.f;
}
__device__ __forceinline__ u16 f2bf(float f) {
  union { uint32_t i; float f; } v; v.f = f;
  uint32_t r = v.i + 0x7fffu + ((v.i >> 16) & 1u);
  return (u16)(r >> 16);
}
__device__ __forceinline__ float sigmoidf_(float x) { return 1.f / (1.f + __expf(-x)); }

__device__ __forceinline__ void gload_lds16(const void* g, void* l) {
  __builtin_amdgcn_global_load_lds(
      (const __attribute__((address_space(1))) void*)g,
      (__attribute__((address_space(3))) void*)l, 16, 0, 0);
}

struct Reg3 { const u16* A; int lda; const u16* B; int ldb; int kt; };

// ---------------------------------------------------------------- GEMM
// C[M,N] = sum_r A_r (M x k_r) * B_r^T (N x k_r), bf16 MFMA, fp32 acc.
// Block: 128 thr = 2 waves (1x2 over N). BM=64, BN=64, BK=64.
// Per wave: 64x32 accumulator = acc[4][2] f32x4; 16 MFMA / 12 ds_reads per
// k-iter. 4-buffer LDS, 2-deep prefetch (stage(ti+2) buf vs laggard iter
// ti-1 buf never collide mod 4), counted vmcnt(16/8/0).
// XOR swizzle (chunk ^= row&7) on both global-src and ds_read sides.
template <int EPI>   // 2: tanh -> fp32 out + bf16 htilde   3: fused LSTM
__global__ __launch_bounds__(128) void gemm_k(Reg3 r0, Reg3 r1, Reg3 r2,
                                              int nmb,
                                              float* __restrict__ Cf,
                                              u16* __restrict__ Cb,
                                              const float* __restrict__ bsum,
                                              float* __restrict__ cst,
                                              float* __restrict__ h32o,
                                              u16* __restrict__ hbfo,
                                              const int tstep) {
  __shared__ u16 smA[NBUF][64 * 64];
  __shared__ u16 smB[NBUF][64 * 64];
  const int tid = threadIdx.x;
  const int lane = tid & 63;
  const int wave = tid >> 6;          // 0..1
  const int m0 = (blockIdx.x % nmb) * 64;
  const int n0 = (blockIdx.x / nmb) * 64;
  const int row16 = lane & 15;
  const int kg = lane >> 4;           // 0..3
  const int nt = r0.kt + r1.kt + r2.kt;

  auto stage = [&](int ti, int buf) {
    const int k01 = r0.kt + r1.kt;
    const u16* Ap = (ti < r0.kt) ? r0.A : (ti < k01) ? r1.A : r2.A;
    const u16* Bp = (ti < r0.kt) ? r0.B : (ti < k01) ? r1.B : r2.B;
    const int lda = (ti < r0.kt) ? r0.lda : (ti < k01) ? r1.lda : r2.lda;
    const int ldb = (ti < r0.kt) ? r0.ldb : (ti < k01) ? r1.ldb : r2.ldb;
    const int base = (ti < r0.kt) ? 0 : (ti < k01) ? r0.kt : k01;
    const int kr = (ti - base) << 6;
#pragma unroll
    for (int j = 0; j < 4; ++j) {     // A: 64x64 bf16 = 512 chunks, 4/thread
      const int c = j * 128 + tid;
      const int row = c >> 3, q = c & 7;
      gload_lds16(Ap + (size_t)(m0 + row) * lda + kr + ((q ^ (row & 7)) << 3),
                  (char*)&smA[buf][0] + (size_t)(j * 128 + wave * 64) * 16);
    }
#pragma unroll
    for (int j = 0; j < 4; ++j) {     // B: 64x64 = 512 chunks, 4/thread
      const int c = j * 128 + tid;
      const int row = c >> 3, q = c & 7;
      gload_lds16(Bp + (size_t)(n0 + row) * ldb + kr + ((q ^ (row & 7)) << 3),
                  (char*)&smB[buf][0] + (size_t)(j * 128 + wave * 64) * 16);
    }
  };

  f32x4 acc[4][2] = {};
  stage(0, 0);
  if (nt > 1) stage(1, 1);
  for (int ti = 0; ti < nt; ++ti) {
    const int buf = ti & 3;
    if (ti + 2 < nt) {
      stage(ti + 2, (ti + 2) & 3);
      asm volatile("s_waitcnt vmcnt(16)" ::: "memory");
    } else if (ti + 1 < nt) {
      asm volatile("s_waitcnt vmcnt(8)" ::: "memory");
    } else {
      asm volatile("s_waitcnt vmcnt(0)" ::: "memory");
    }
    __builtin_amdgcn_s_barrier();
    __builtin_amdgcn_sched_barrier(0);
#pragma unroll
    for (int ks = 0; ks < 2; ++ks) {
      short8 af[4], bfr[2];
#pragma unroll
      for (int mi = 0; mi < 4; ++mi) {
        const int R = mi * 16 + row16;
        af[mi] = *(const short8*)((const char*)&smA[buf][0] +
                                  (size_t)(((R << 3) | ((ks * 4 + kg) ^ (R & 7))) << 4));
      }
#pragma unroll
      for (int ni = 0; ni < 2; ++ni) {
        const int R = wave * 32 + ni * 16 + row16;
        bfr[ni] = *(const short8*)((const char*)&smB[buf][0] +
                                   (size_t)(((R << 3) | ((ks * 4 + kg) ^ (R & 7))) << 4));
      }
      asm volatile("s_waitcnt lgkmcnt(0)" ::: "memory");
      __builtin_amdgcn_sched_barrier(0);
#pragma unroll
      for (int mi = 0; mi < 4; ++mi)
#pragma unroll
        for (int ni = 0; ni < 2; ++ni)
          acc[mi][ni] = __builtin_amdgcn_mfma_f32_16x16x32_bf16(af[mi], bfr[ni], acc[mi][ni], 0, 0, 0);
      __builtin_amdgcn_sched_barrier(0);
    }
  }
  // C/D layout: col = lane&15, row = (lane>>4)*4 + r  [m89-verified]
#pragma unroll
  for (int mi = 0; mi < 4; ++mi) {
#pragma unroll
    for (int ni = 0; ni < 2; ++ni) {
#pragma unroll
      for (int r = 0; r < 4; ++r) {
        const int row = m0 + mi * 16 + (kg << 2) + r;
        const int col = n0 + wave * 32 + ni * 16 + row16;
        float v = acc[mi][ni][r];
        if (EPI == 2) {
          float tv = tanhf(v);
          Cf[(size_t)row * (T_ * H_) + (size_t)tstep * H_ + col] = tv;
          Cb[row * H_ + col] = f2bf(tv);
        } else {
          // gate-interleaved: col&3 = gate(i,f,g,o), col>>2 = unit
          v += bsum[col];
          float v1 = __shfl_xor(v, 1);
          float v2 = __shfl_xor(v, 2);
          float v3 = __shfl_xor(v, 3);
          if ((lane & 3) == 0) {
            const int u = col >> 2;
            float iv = sigmoidf_(v);
            float fv = sigmoidf_(v1);
            float gv = tanhf(v2);
            float ov = sigmoidf_(v3);
            float cn = fv * cst[row * H_ + u] + iv * gv;
            float hn = ov * tanhf(cn);
            cst[row * H_ + u] = cn;
            h32o[row * H_ + u] = hn;
            hbfo[row * H_ + u] = f2bf(hn);
          }
        }
      }
    }
  }
}

// ---------------------------------------------------------------- attention
// One block per batch row, 1024 thr (16 waves).
// Phase 1: target = h @ W_in^T as GEMV over k-tiled W_inT[k8][n][8].
// Phase 2: online-softmax over bf16 ctx rows (wave-strided), fp32 target.
// Phase 3: 16->8 LDS merge (permuted facc), normalize, bf16 weighted out.
__device__ __forceinline__ int fidx(int lane, int j) {
  return (j << 6) + ((lane + (j << 2)) & 63);
}

__global__ __launch_bounds__(1024) void attn_k(const u16* __restrict__ hbf,
                                               const u16* __restrict__ WinT,
                                               const u16* __restrict__ ctxb,
                                               const int* __restrict__ src_len,
                                               u16* __restrict__ wwbf) {
  __shared__ float hsm[1024];
  __shared__ float tgtp[1024 + 64];
  __shared__ float facc[8][1024];
  __shared__ float fm[16], fl[16];
  const int b = blockIdx.x;
  const int tid = threadIdx.x;
  const int lane = tid & 63;
  const int wave = tid >> 6;
  const int len = src_len[b];

  hsm[tid] = bf2f(hbf[b * H_ + tid]);
  __syncthreads();

  {  // GEMV: thread tid owns target[tid]
    float a = 0.f;
    const u16* wp = WinT + tid * 8;
    for (int k8 = 0; k8 < 128; ++k8) {
      short8 wv = *(const short8*)(wp + (size_t)k8 * 8192);
      float4 h0v = *(const float4*)&hsm[k8 * 8];
      float4 h1v = *(const float4*)&hsm[k8 * 8 + 4];
      a += bf2f((u16)wv[0]) * h0v.x + bf2f((u16)wv[1]) * h0v.y
         + bf2f((u16)wv[2]) * h0v.z + bf2f((u16)wv[3]) * h0v.w
         + bf2f((u16)wv[4]) * h1v.x + bf2f((u16)wv[5]) * h1v.y
         + bf2f((u16)wv[6]) * h1v.z + bf2f((u16)wv[7]) * h1v.w;
    }
    tgtp[tid + (tid >> 4)] = a;   // padded: idx = n + n/16
  }
  __syncthreads();

  float tg[16];
#pragma unroll
  for (int j = 0; j < 16; ++j) tg[j] = tgtp[lane * 17 + j];

  float m = -1e30f, l = 0.f;
  float acc[16];
#pragma unroll
  for (int j = 0; j < 16; ++j) acc[j] = 0.f;

  for (int s = wave; s < len; s += 16) {
    const u16* cr = ctxb + (((size_t)b * S_ + s) << 10) + (lane << 4);
    short8 v1 = *(const short8*)cr;
    short8 v2 = *(const short8*)(cr + 8);
    float cf[16];
#pragma unroll
    for (int j = 0; j < 8; ++j) { cf[j] = bf2f((u16)v1[j]); cf[8 + j] = bf2f((u16)v2[j]); }
    float x = 0.f;
#pragma unroll
    for (int j = 0; j < 16; ++j) x += cf[j] * tg[j];
#pragma unroll
    for (int off = 1; off < 64; off <<= 1) x += __shfl_xor(x, off);
    if (x > m) {                      // wave-uniform after reduce
      float sc_ = __expf(m - x);
      l *= sc_;
#pragma unroll
      for (int j = 0; j < 16; ++j) acc[j] *= sc_;
      m = x;
    }
    float p = __expf(x - m);
    l += p;
#pragma unroll
    for (int j = 0; j < 16; ++j) acc[j] += p * cf[j];
  }

  if (wave >= 8) {
#pragma unroll
    for (int j = 0; j < 16; ++j) facc[wave - 8][fidx(lane, j)] = acc[j];
    if (lane == 0) { fm[wave] = m; fl[wave] = l; }
  }
  __syncthreads();
  if (wave < 8) {
    float pm = fm[8 + wave];
    float pl = fl[8 + wave];
    float M = fmaxf(m, pm);
    float e1 = __expf(m - M);
    float e2 = __expf(pm - M);
#pragma unroll
    for (int j = 0; j < 16; ++j) {
      float pv = facc[wave][fidx(lane, j)];
      facc[wave][fidx(lane, j)] = acc[j] * e1 + pv * e2;
    }
    if (lane == 0) { fm[wave] = M; fl[wave] = l * e1 + pl * e2; }
  }
  __syncthreads();
  float mstar = -1e30f;
#pragma unroll
  for (int w = 0; w < 8; ++w) mstar = fmaxf(mstar, fm[w]);
  float lsum = 0.f, asum = 0.f;
  const int ri = fidx(tid >> 4, tid & 15);
#pragma unroll
  for (int w = 0; w < 8; ++w) {
    float e = __expf(fm[w] - mstar);
    lsum += fl[w] * e;
    asum += facc[w][ri] * e;
  }
  wwbf[b * H_ + tid] = f2bf(asum / lsum);
}

// ---------------------------------------------------------------- converts
__global__ __launch_bounds__(256) void convert_all(
    const float* __restrict__ W_ih, const float* __restrict__ W_hh,
    const float* __restrict__ W_in, const float* __restrict__ W_out,
    const float* __restrict__ trg_emb, const float* __restrict__ ctx,
    const float* __restrict__ b_ih, const float* __restrict__ b_hh,
    const float* __restrict__ h0, const float* __restrict__ c0,
    u16* __restrict__ wWih, u16* __restrict__ wWhh, u16* __restrict__ wWinT,
    u16* __restrict__ wWout, u16* __restrict__ wemb, u16* __restrict__ wctx,
    float* __restrict__ wbsum, u16* __restrict__ wh0, u16* __restrict__ whtbf,
    float* __restrict__ wc) {
  const int gtid = blockIdx.x * 256 + threadIdx.x;
  const int GSZ = 2048 * 256;
  auto cvt4 = [](float4 v) {
    ushort4 o; o.x = f2bf(v.x); o.y = f2bf(v.y); o.z = f2bf(v.z); o.w = f2bf(v.w);
    return o;
  };
  for (int i = gtid; i < 1572864; i += GSZ) {     // W_ih gi (4096x1536)
    const int r = i / 384, c4 = i - r * 384;
    const int rp = ((r & 1023) << 2) + (r >> 10);
    ((ushort4*)wWih)[(size_t)rp * 384 + c4] = cvt4(((const float4*)W_ih)[i]);
  }
  for (int i = gtid; i < 1048576; i += GSZ) {     // W_hh gi (4096x1024)
    const int r = i >> 8, c4 = i & 255;
    const int rp = ((r & 1023) << 2) + (r >> 10);
    ((ushort4*)wWhh)[(size_t)rp * 256 + c4] = cvt4(((const float4*)W_hh)[i]);
  }
  for (int i = gtid; i < 524288; i += GSZ)        // W_out (1024x2048)
    ((ushort4*)wWout)[i] = cvt4(((const float4*)W_out)[i]);
  for (int i = gtid; i < 524288; i += GSZ)        // emb (B,T,E)
    ((ushort4*)wemb)[i] = cvt4(((const float4*)trg_emb)[i]);
  for (int i = gtid; i < 131072; i += GSZ) {      // W_inT k-tiled [k8][n][8]
    const int n = i >> 7, k8 = i & 127;
    const float* s = W_in + (size_t)n * 1024 + k8 * 8;
    ushort4* d = (ushort4*)(wWinT + (size_t)k8 * 8192 + n * 8);
    d[0] = cvt4(*(const float4*)s);
    d[1] = cvt4(*(const float4*)(s + 4));
  }
  for (int i = gtid; i < 33554432; i += GSZ)      // ctx -> bf16 (B,S,H)
    ((ushort4*)wctx)[i] = cvt4(((const float4*)ctx)[i]);
  if (gtid < 4096) {                              // bias (gi)
    const int cp = ((gtid & 1023) << 2) + (gtid >> 10);
    wbsum[cp] = b_ih[gtid] + b_hh[gtid];
  }
  for (int i = gtid; i < 262144; i += GSZ) {      // state init
    u16 hb = f2bf(h0[i]);
    wh0[i] = hb;
    whtbf[i] = hb;
    wc[i] = c0[i];
  }
}

// ---------------------------------------------------------------- host
extern "C" void kernel_launch(void* const* d_in, const int* in_sizes, int n_in,
                              void* d_out, int out_size, void* d_ws, size_t ws_size,
                              hipStream_t stream) {
  const float* trg_emb = (const float*)d_in[0];
  const float* h0      = (const float*)d_in[1];
  const float* c0      = (const float*)d_in[2];
  const float* ctx     = (const float*)d_in[3];
  const int*   src_len = (const int*)d_in[4];
  const float* W_ih    = (const float*)d_in[5];
  const float* W_hh    = (const float*)d_in[6];
  const float* b_ih    = (const float*)d_in[7];
  const float* b_hh    = (const float*)d_in[8];
  const float* W_in    = (const float*)d_in[9];
  const float* W_out   = (const float*)d_in[10];
  float* out = (float*)d_out;

  char* w = (char*)d_ws;
  size_t off = 0;
  auto alloc = [&](size_t bytes) { char* p = w + off; off += bytes; return p; };
  u16*   wWih  = (u16*)  alloc(12582912);   // 4096x1536 bf16 (gi rows)
  u16*   wWhh  = (u16*)  alloc(8388608);    // 4096x1024 bf16 (gi rows)
  u16*   wWinT = (u16*)  alloc(2097152);    // k-tiled [128][1024][8]
  u16*   wWout = (u16*)  alloc(4194304);    // 1024x2048
  u16*   wemb  = (u16*)  alloc(4194304);    // (B,T,E) bf16
  float* wbsum = (float*)alloc(16384);
  float* wh32  = (float*)alloc(1048576);
  float* wc    = (float*)alloc(1048576);
  u16*   wh0   = (u16*)  alloc(524288);     // h ping
  u16*   wh1   = (u16*)  alloc(524288);     // h pong
  u16*   whtbf = (u16*)  alloc(524288);
  u16*   wwbf  = (u16*)  alloc(524288);
  u16*   wctx  = (u16*)  alloc(268435456);  // ctx bf16 (B,S,H)
  (void)ws_size;

  convert_all<<<dim3(2048), dim3(256), 0, stream>>>(
      W_ih, W_hh, W_in, W_out, trg_emb, ctx, b_ih, b_hh, h0, c0,
      wWih, wWhh, wWinT, wWout, wemb, wctx, wbsum, wh0, whtbf, wc);

  Reg3 rz = { nullptr, 0, nullptr, 0, 0 };
  for (int t = 0; t < T_; ++t) {
    const u16* hcur = (t & 1) ? wh1 : wh0;
    u16* hnxt = (t & 1) ? wh0 : wh1;
    // gates = [emb_t | htilde | h] @ [W_ihE | W_ihH | W_hh]^T (+bias) -> LSTM
    Reg3 g0 = { wemb + (size_t)t * E_, T_ * E_, wWih,      E_ + H_, 8 };
    Reg3 g1 = { whtbf,                 H_,      wWih + E_, E_ + H_, 16 };
    Reg3 g2 = { hcur,                  H_,      wWhh,      H_,      16 };
    gemm_k<3><<<dim3(256), dim3(128), 0, stream>>>(
        g0, g1, g2, 4, nullptr, nullptr, wbsum, wc, wh32, hnxt, 0);
    // attn: W_in GEMV + online-softmax + weighted (bf16 ctx)
    attn_k<<<dim3(B_), dim3(1024), 0, stream>>>(hnxt, wWinT, wctx, src_len, wwbf);
    // htilde = tanh([weighted | h] @ W_out^T) -> out[:,t,:] + feedback
    Reg3 o0 = { wwbf, H_, wWout,      2 * H_, 16 };
    Reg3 o1 = { hnxt, H_, wWout + H_, 2 * H_, 16 };
    gemm_k<2><<<dim3(64), dim3(128), 0, stream>>>(
        o0, o1, rz, 4, out, whtbf, nullptr, nullptr, nullptr, nullptr, t);
  }
  hipMemcpyAsync(out + (size_t)B_ * T_ * H_, wh32, (size_t)B_ * H_ * sizeof(float),
                 hipMemcpyDeviceToDevice, stream);
  hipMemcpyAsync(out + (size_t)B_ * T_ * H_ + B_ * H_, wc, (size_t)B_ * H_ * sizeof(float),
                 hipMemcpyDeviceToDevice, stream);
}

// Round 10
// 2096.280 us; speedup vs baseline: 2.5829x; 1.0670x over previous
//
#include <hip/hip_runtime.h>
#include <cstdint>
#include <cstddef>

// CCDecoder: 16-step input-feeding LSTM + Luong attention decoder.
// B=256, S=512, T=16, H=1024, E=512.
// R10 = R9 with two fixes from the R9 post-mortem:
//   1. W_in GEMV un-fused: R9's per-block GEMV streamed 2MB x 256 blocks =
//      512 MB/step of L2/L3 traffic (~40us/step). Separate gemm_k<1>
//      (64 blocks) reads W_in ONCE (2MB/step).
//   2. ctx compacted (only rows s < len[b], exclusive-scan offsets) ->
//      touched ctx ~134 MB avg -> L3-resident with weights; attention
//      reads at L3 BW after first touch.
//   Structure otherwise R9-proven: 64x32 acc/wave GEMM (BM/BN/BK=64,
//   NBUF=4, 2-deep prefetch, counted vmcnt 16/8/0), fused LSTM epilogue,
//   online-softmax attn, h ping-pong. 4 launches/step.

#define B_ 256
#define S_ 512
#define T_ 16
#define H_ 1024
#define E_ 512
#define NBUF 4

typedef unsigned short u16;
using short8 = __attribute__((ext_vector_type(8))) short;
using f32x4  = __attribute__((ext_vector_type(4))) float;

__device__ __forceinline__ float bf2f(u16 u) {
  union { uint32_t i; float f; } v; v.i = ((uint32_t)u) << 16; return v.f;
}
__device__ __forceinline__ u16 f2bf(float f) {
  union { uint32_t i; float f; } v; v.f = f;
  uint32_t r = v.i + 0x7fffu + ((v.i >> 16) & 1u);
  return (u16)(r >> 16);
}
__device__ __forceinline__ ushort4 cvt4bf(float4 v) {
  ushort4 o; o.x = f2bf(v.x); o.y = f2bf(v.y); o.z = f2bf(v.z); o.w = f2bf(v.w);
  return o;
}
__device__ __forceinline__ float sigmoidf_(float x) { return 1.f / (1.f + __expf(-x)); }

__device__ __forceinline__ void gload_lds16(const void* g, void* l) {
  __builtin_amdgcn_global_load_lds(
      (const __attribute__((address_space(1))) void*)g,
      (__attribute__((address_space(3))) void*)l, 16, 0, 0);
}

struct Reg3 { const u16* A; int lda; const u16* B; int ldb; int kt; };

// ---------------------------------------------------------------- GEMM
// C[M,N] = sum_r A_r (M x k_r) * B_r^T (N x k_r), bf16 MFMA, fp32 acc.
// Block: 128 thr = 2 waves (1x2 over N). BM=64, BN=64, BK=64.
// Per wave: 64x32 acc = acc[4][2] f32x4; 16 MFMA / 12 ds_reads per k-iter.
// NBUF=4, 2-deep prefetch (stage(ti+2) vs laggard reads(ti-1) never collide
// mod 4), counted vmcnt(16/8/0). XOR swizzle both sides.
template <int EPI>   // 1: bf16->Cb  2: tanh->fp32 out+bf16 htilde  3: fused LSTM
__global__ __launch_bounds__(128) void gemm_k(Reg3 r0, Reg3 r1, Reg3 r2,
                                              int nmb,
                                              float* __restrict__ Cf,
                                              u16* __restrict__ Cb,
                                              const float* __restrict__ bsum,
                                              float* __restrict__ cst,
                                              float* __restrict__ h32o,
                                              u16* __restrict__ hbfo,
                                              const int tstep) {
  __shared__ u16 smA[NBUF][64 * 64];
  __shared__ u16 smB[NBUF][64 * 64];
  const int tid = threadIdx.x;
  const int lane = tid & 63;
  const int wave = tid >> 6;          // 0..1
  const int m0 = (blockIdx.x % nmb) * 64;
  const int n0 = (blockIdx.x / nmb) * 64;
  const int row16 = lane & 15;
  const int kg = lane >> 4;           // 0..3
  const int nt = r0.kt + r1.kt + r2.kt;

  auto stage = [&](int ti, int buf) {
    const int k01 = r0.kt + r1.kt;
    const u16* Ap = (ti < r0.kt) ? r0.A : (ti < k01) ? r1.A : r2.A;
    const u16* Bp = (ti < r0.kt) ? r0.B : (ti < k01) ? r1.B : r2.B;
    const int lda = (ti < r0.kt) ? r0.lda : (ti < k01) ? r1.lda : r2.lda;
    const int ldb = (ti < r0.kt) ? r0.ldb : (ti < k01) ? r1.ldb : r2.ldb;
    const int base = (ti < r0.kt) ? 0 : (ti < k01) ? r0.kt : k01;
    const int kr = (ti - base) << 6;
#pragma unroll
    for (int j = 0; j < 4; ++j) {     // A: 64x64 bf16 = 512 chunks, 4/thread
      const int c = j * 128 + tid;
      const int row = c >> 3, q = c & 7;
      gload_lds16(Ap + (size_t)(m0 + row) * lda + kr + ((q ^ (row & 7)) << 3),
                  (char*)&smA[buf][0] + (size_t)(j * 128 + wave * 64) * 16);
    }
#pragma unroll
    for (int j = 0; j < 4; ++j) {     // B: 64x64 = 512 chunks, 4/thread
      const int c = j * 128 + tid;
      const int row = c >> 3, q = c & 7;
      gload_lds16(Bp + (size_t)(n0 + row) * ldb + kr + ((q ^ (row & 7)) << 3),
                  (char*)&smB[buf][0] + (size_t)(j * 128 + wave * 64) * 16);
    }
  };

  f32x4 acc[4][2] = {};
  stage(0, 0);
  if (nt > 1) stage(1, 1);
  for (int ti = 0; ti < nt; ++ti) {
    const int buf = ti & 3;
    if (ti + 2 < nt) {
      stage(ti + 2, (ti + 2) & 3);
      asm volatile("s_waitcnt vmcnt(16)" ::: "memory");
    } else if (ti + 1 < nt) {
      asm volatile("s_waitcnt vmcnt(8)" ::: "memory");
    } else {
      asm volatile("s_waitcnt vmcnt(0)" ::: "memory");
    }
    __builtin_amdgcn_s_barrier();
    __builtin_amdgcn_sched_barrier(0);
#pragma unroll
    for (int ks = 0; ks < 2; ++ks) {
      short8 af[4], bfr[2];
#pragma unroll
      for (int mi = 0; mi < 4; ++mi) {
        const int R = mi * 16 + row16;
        af[mi] = *(const short8*)((const char*)&smA[buf][0] +
                                  (size_t)(((R << 3) | ((ks * 4 + kg) ^ (R & 7))) << 4));
      }
#pragma unroll
      for (int ni = 0; ni < 2; ++ni) {
        const int R = wave * 32 + ni * 16 + row16;
        bfr[ni] = *(const short8*)((const char*)&smB[buf][0] +
                                   (size_t)(((R << 3) | ((ks * 4 + kg) ^ (R & 7))) << 4));
      }
      asm volatile("s_waitcnt lgkmcnt(0)" ::: "memory");
      __builtin_amdgcn_sched_barrier(0);
#pragma unroll
      for (int mi = 0; mi < 4; ++mi)
#pragma unroll
        for (int ni = 0; ni < 2; ++ni)
          acc[mi][ni] = __builtin_amdgcn_mfma_f32_16x16x32_bf16(af[mi], bfr[ni], acc[mi][ni], 0, 0, 0);
      __builtin_amdgcn_sched_barrier(0);
    }
  }
  // C/D layout: col = lane&15, row = (lane>>4)*4 + r  [m89-verified]
#pragma unroll
  for (int mi = 0; mi < 4; ++mi) {
#pragma unroll
    for (int ni = 0; ni < 2; ++ni) {
#pragma unroll
      for (int r = 0; r < 4; ++r) {
        const int row = m0 + mi * 16 + (kg << 2) + r;
        const int col = n0 + wave * 32 + ni * 16 + row16;
        float v = acc[mi][ni][r];
        if (EPI == 1) {
          Cb[row * H_ + col] = f2bf(v);
        } else if (EPI == 2) {
          float tv = tanhf(v);
          Cf[(size_t)row * (T_ * H_) + (size_t)tstep * H_ + col] = tv;
          Cb[row * H_ + col] = f2bf(tv);
        } else {
          // gate-interleaved: col&3 = gate(i,f,g,o), col>>2 = unit
          v += bsum[col];
          float v1 = __shfl_xor(v, 1);
          float v2 = __shfl_xor(v, 2);
          float v3 = __shfl_xor(v, 3);
          if ((lane & 3) == 0) {
            const int u = col >> 2;
            float iv = sigmoidf_(v);
            float fv = sigmoidf_(v1);
            float gv = tanhf(v2);
            float ov = sigmoidf_(v3);
            float cn = fv * cst[row * H_ + u] + iv * gv;
            float hn = ov * tanhf(cn);
            cst[row * H_ + u] = cn;
            h32o[row * H_ + u] = hn;
            hbfo[row * H_ + u] = f2bf(hn);
          }
        }
      }
    }
  }
}

// ---------------------------------------------------------------- attention
// One block per batch row, 1024 thr (16 waves). Online-softmax over
// compacted bf16 ctx rows (wave-strided); target from wtgt (bf16);
// 16->8 LDS merge (permuted facc), normalize, bf16 weighted out.
__device__ __forceinline__ int fidx(int lane, int j) {
  return (j << 6) + ((lane + (j << 2)) & 63);
}

__global__ __launch_bounds__(1024) void attn_k(const u16* __restrict__ tgt,
                                               const u16* __restrict__ ctxc,
                                               const int* __restrict__ offs,
                                               const int* __restrict__ src_len,
                                               u16* __restrict__ wwbf) {
  __shared__ float facc[8][1024];
  __shared__ float fm[16], fl[16];
  const int b = blockIdx.x;
  const int tid = threadIdx.x;
  const int lane = tid & 63;
  const int wave = tid >> 6;
  const int len = src_len[b];
  const u16* cb = ctxc + ((size_t)offs[b] << 10);

  float tg[16];
  {
    const u16* tp = tgt + b * H_ + lane * 16;
    short8 v1 = *(const short8*)tp;
    short8 v2 = *(const short8*)(tp + 8);
#pragma unroll
    for (int j = 0; j < 8; ++j) { tg[j] = bf2f((u16)v1[j]); tg[8 + j] = bf2f((u16)v2[j]); }
  }

  float m = -1e30f, l = 0.f;
  float acc[16];
#pragma unroll
  for (int j = 0; j < 16; ++j) acc[j] = 0.f;

  for (int s = wave; s < len; s += 16) {
    const u16* cr = cb + ((size_t)s << 10) + (lane << 4);
    short8 v1 = *(const short8*)cr;
    short8 v2 = *(const short8*)(cr + 8);
    float cf[16];
#pragma unroll
    for (int j = 0; j < 8; ++j) { cf[j] = bf2f((u16)v1[j]); cf[8 + j] = bf2f((u16)v2[j]); }
    float x = 0.f;
#pragma unroll
    for (int j = 0; j < 16; ++j) x += cf[j] * tg[j];
#pragma unroll
    for (int off = 1; off < 64; off <<= 1) x += __shfl_xor(x, off);
    if (x > m) {                      // wave-uniform after reduce
      float sc_ = __expf(m - x);
      l *= sc_;
#pragma unroll
      for (int j = 0; j < 16; ++j) acc[j] *= sc_;
      m = x;
    }
    float p = __expf(x - m);
    l += p;
#pragma unroll
    for (int j = 0; j < 16; ++j) acc[j] += p * cf[j];
  }

  if (wave >= 8) {
#pragma unroll
    for (int j = 0; j < 16; ++j) facc[wave - 8][fidx(lane, j)] = acc[j];
    if (lane == 0) { fm[wave] = m; fl[wave] = l; }
  }
  __syncthreads();
  if (wave < 8) {
    float pm = fm[8 + wave];
    float pl = fl[8 + wave];
    float M = fmaxf(m, pm);
    float e1 = __expf(m - M);
    float e2 = __expf(pm - M);
#pragma unroll
    for (int j = 0; j < 16; ++j) {
      float pv = facc[wave][fidx(lane, j)];
      facc[wave][fidx(lane, j)] = acc[j] * e1 + pv * e2;
    }
    if (lane == 0) { fm[wave] = M; fl[wave] = l * e1 + pl * e2; }
  }
  __syncthreads();
  float mstar = -1e30f;
#pragma unroll
  for (int w = 0; w < 8; ++w) mstar = fmaxf(mstar, fm[w]);
  float lsum = 0.f, asum = 0.f;
  const int ri = fidx(tid >> 4, tid & 15);
#pragma unroll
  for (int w = 0; w < 8; ++w) {
    float e = __expf(fm[w] - mstar);
    lsum += fl[w] * e;
    asum += facc[w][ri] * e;
  }
  wwbf[b * H_ + tid] = f2bf(asum / lsum);
}

// ---------------------------------------------------------------- scan
// Exclusive prefix sum of src_len (256 entries), one block.
__global__ __launch_bounds__(256) void scan_k(const int* __restrict__ len,
                                              int* __restrict__ offs) {
  __shared__ int tmp[256];
  const int tid = threadIdx.x;
  const int v = len[tid];
  tmp[tid] = v;
  __syncthreads();
  for (int off = 1; off < 256; off <<= 1) {
    int t = (tid >= off) ? tmp[tid - off] : 0;
    __syncthreads();
    tmp[tid] += t;
    __syncthreads();
  }
  offs[tid] = tmp[tid] - v;   // exclusive
}

// ---------------------------------------------------------------- compaction
// One block per b: copy rows s<len[b] of ctx (fp32) to compacted bf16.
__global__ __launch_bounds__(256) void ctx_compact(const float* __restrict__ ctx,
                                                   const int* __restrict__ src_len,
                                                   const int* __restrict__ offs,
                                                   u16* __restrict__ ctxc) {
  const int b = blockIdx.x;
  const int n4 = src_len[b] << 8;     // len*1024/4 vec4s
  const float4* s = (const float4*)(ctx + ((size_t)b << 19));
  ushort4* d = (ushort4*)(ctxc + ((size_t)offs[b] << 10));
  for (int i = threadIdx.x; i < n4; i += 256) d[i] = cvt4bf(s[i]);
}

// ---------------------------------------------------------------- converts
__global__ __launch_bounds__(256) void convert_all(
    const float* __restrict__ W_ih, const float* __restrict__ W_hh,
    const float* __restrict__ W_in, const float* __restrict__ W_out,
    const float* __restrict__ trg_emb,
    const float* __restrict__ b_ih, const float* __restrict__ b_hh,
    const float* __restrict__ h0, const float* __restrict__ c0,
    u16* __restrict__ wWih, u16* __restrict__ wWhh, u16* __restrict__ wWin,
    u16* __restrict__ wWout, u16* __restrict__ wemb,
    float* __restrict__ wbsum, u16* __restrict__ wh0, u16* __restrict__ whtbf,
    float* __restrict__ wc) {
  const int gtid = blockIdx.x * 256 + threadIdx.x;
  const int GSZ = 1024 * 256;
  for (int i = gtid; i < 1572864; i += GSZ) {     // W_ih gi (4096x1536)
    const int r = i / 384, c4 = i - r * 384;
    const int rp = ((r & 1023) << 2) + (r >> 10);
    ((ushort4*)wWih)[(size_t)rp * 384 + c4] = cvt4bf(((const float4*)W_ih)[i]);
  }
  for (int i = gtid; i < 1048576; i += GSZ) {     // W_hh gi (4096x1024)
    const int r = i >> 8, c4 = i & 255;
    const int rp = ((r & 1023) << 2) + (r >> 10);
    ((ushort4*)wWhh)[(size_t)rp * 256 + c4] = cvt4bf(((const float4*)W_hh)[i]);
  }
  for (int i = gtid; i < 262144; i += GSZ)        // W_in (1024x1024)
    ((ushort4*)wWin)[i] = cvt4bf(((const float4*)W_in)[i]);
  for (int i = gtid; i < 524288; i += GSZ)        // W_out (1024x2048)
    ((ushort4*)wWout)[i] = cvt4bf(((const float4*)W_out)[i]);
  for (int i = gtid; i < 524288; i += GSZ)        // emb (B,T,E)
    ((ushort4*)wemb)[i] = cvt4bf(((const float4*)trg_emb)[i]);
  if (gtid < 4096) {                              // bias (gi)
    const int cp = ((gtid & 1023) << 2) + (gtid >> 10);
    wbsum[cp] = b_ih[gtid] + b_hh[gtid];
  }
  for (int i = gtid; i < 262144; i += GSZ) {      // state init
    u16 hb = f2bf(h0[i]);
    wh0[i] = hb;
    whtbf[i] = hb;
    wc[i] = c0[i];
  }
}

// ---------------------------------------------------------------- host
extern "C" void kernel_launch(void* const* d_in, const int* in_sizes, int n_in,
                              void* d_out, int out_size, void* d_ws, size_t ws_size,
                              hipStream_t stream) {
  const float* trg_emb = (const float*)d_in[0];
  const float* h0      = (const float*)d_in[1];
  const float* c0      = (const float*)d_in[2];
  const float* ctx     = (const float*)d_in[3];
  const int*   src_len = (const int*)d_in[4];
  const float* W_ih    = (const float*)d_in[5];
  const float* W_hh    = (const float*)d_in[6];
  const float* b_ih    = (const float*)d_in[7];
  const float* b_hh    = (const float*)d_in[8];
  const float* W_in    = (const float*)d_in[9];
  const float* W_out   = (const float*)d_in[10];
  float* out = (float*)d_out;

  char* w = (char*)d_ws;
  size_t off = 0;
  auto alloc = [&](size_t bytes) { char* p = w + off; off += bytes; return p; };
  u16*   wWih  = (u16*)  alloc(12582912);   // 4096x1536 bf16 (gi rows)
  u16*   wWhh  = (u16*)  alloc(8388608);    // 4096x1024 bf16 (gi rows)
  u16*   wWin  = (u16*)  alloc(2097152);    // 1024x1024
  u16*   wWout = (u16*)  alloc(4194304);    // 1024x2048
  u16*   wemb  = (u16*)  alloc(4194304);    // (B,T,E) bf16
  float* wbsum = (float*)alloc(16384);
  float* wh32  = (float*)alloc(1048576);
  float* wc    = (float*)alloc(1048576);
  u16*   wh0   = (u16*)  alloc(524288);     // h ping
  u16*   wh1   = (u16*)  alloc(524288);     // h pong
  u16*   whtbf = (u16*)  alloc(524288);
  u16*   wtgt  = (u16*)  alloc(524288);
  u16*   wwbf  = (u16*)  alloc(524288);
  int*   woffs = (int*)  alloc(1024);
  u16*   wctxc = (u16*)  alloc(268435456);  // compacted ctx bf16 (worst case)
  (void)ws_size;

  scan_k<<<dim3(1), dim3(256), 0, stream>>>(src_len, woffs);
  convert_all<<<dim3(1024), dim3(256), 0, stream>>>(
      W_ih, W_hh, W_in, W_out, trg_emb, b_ih, b_hh, h0, c0,
      wWih, wWhh, wWin, wWout, wemb, wbsum, wh0, whtbf, wc);
  ctx_compact<<<dim3(B_), dim3(256), 0, stream>>>(ctx, src_len, woffs, wctxc);

  Reg3 rz = { nullptr, 0, nullptr, 0, 0 };
  for (int t = 0; t < T_; ++t) {
    const u16* hcur = (t & 1) ? wh1 : wh0;
    u16* hnxt = (t & 1) ? wh0 : wh1;
    // gates = [emb_t | htilde | h] @ [W_ihE | W_ihH | W_hh]^T (+bias) -> LSTM
    Reg3 g0 = { wemb + (size_t)t * E_, T_ * E_, wWih,      E_ + H_, 8 };
    Reg3 g1 = { whtbf,                 H_,      wWih + E_, E_ + H_, 16 };
    Reg3 g2 = { hcur,                  H_,      wWhh,      H_,      16 };
    gemm_k<3><<<dim3(256), dim3(128), 0, stream>>>(
        g0, g1, g2, 4, nullptr, nullptr, wbsum, wc, wh32, hnxt, 0);
    // target = h @ W_in^T  (M=256, N=1024, K=1024; weights read once)
    Reg3 i0 = { hnxt, H_, wWin, H_, 16 };
    gemm_k<1><<<dim3(64), dim3(128), 0, stream>>>(
        i0, rz, rz, 4, nullptr, wtgt, nullptr, nullptr, nullptr, nullptr, 0);
    // attn: online-softmax + weighted over compacted bf16 ctx
    attn_k<<<dim3(B_), dim3(1024), 0, stream>>>(wtgt, wctxc, woffs, src_len, wwbf);
    // htilde = tanh([weighted | h] @ W_out^T) -> out[:,t,:] + feedback
    Reg3 o0 = { wwbf, H_, wWout,      2 * H_, 16 };
    Reg3 o1 = { hnxt, H_, wWout + H_, 2 * H_, 16 };
    gemm_k<2><<<dim3(64), dim3(128), 0, stream>>>(
        o0, o1, rz, 4, out, whtbf, nullptr, nullptr, nullptr, nullptr, t);
  }
  hipMemcpyAsync(out + (size_t)B_ * T_ * H_, wh32, (size_t)B_ * H_ * sizeof(float),
                 hipMemcpyDeviceToDevice, stream);
  hipMemcpyAsync(out + (size_t)B_ * T_ * H_ + B_ * H_, wc, (size_t)B_ * H_ * sizeof(float),
                 hipMemcpyDeviceToDevice, stream);
}